// Round 11
// baseline (1744.757 us; speedup 1.0000x reference)
//
#include <hip/hip_runtime.h>

// 3-layer LSTM encoder. B=512, T=512, F=8, HID=128, EMB=64.
// R11: software dual-streaming — each block owns TWO batch tiles; layer
// weights shared (register-resident once), per-tile state duplicated with
// static names. Every barrier interval advances both tiles one step: the two
// independent chains interleave so latency of one hides under issue of the
// other. 48 blocks = 3 stages x 16 pair-blocks. Flag pipeline as R8/R10.
// ws: [O1 67MB][O2 67MB][flags]

#define DEVI __device__ __forceinline__

typedef _Float16 h8 __attribute__((ext_vector_type(8)));
typedef float f4 __attribute__((ext_vector_type(4)));

static constexpr int T_ = 512, TC_ = 16, NC_ = T_ / TC_;

DEVI float sigmoidf_(float x) {
    return __builtin_amdgcn_rcpf(1.f + __builtin_amdgcn_exp2f(x * -1.44269504f));
}
DEVI float tanhf_(float x) {
    return 2.f * __builtin_amdgcn_rcpf(1.f + __builtin_amdgcn_exp2f(x * -2.88539008f)) - 1.f;
}

DEVI h8 cvt8(const float* p) {
    const float4 a = *reinterpret_cast<const float4*>(p);
    const float4 b = *reinterpret_cast<const float4*>(p + 4);
    return h8{(_Float16)a.x, (_Float16)a.y, (_Float16)a.z, (_Float16)a.w,
              (_Float16)b.x, (_Float16)b.y, (_Float16)b.z, (_Float16)b.w};
}

// LDS-only barrier: orders h_lds writes/reads without draining vmcnt.
DEVI void lds_barrier() {
    asm volatile("s_waitcnt lgkmcnt(0)\n\ts_barrier" ::: "memory");
}

// LAYER=1: H=128, x from f32 input (K=8 zero-padded), producer only
// LAYER=2: H=128, x from O1, writes O2, consumer+producer
// LAYER=3: H=64,  x from O2, writes out (t=511), consumer only
template <int LAYER>
DEVI void stage2(int tA, int tB, char* smem, const float* x, const _Float16* Oin,
                 _Float16* Oout, const float* Wih, const float* Whh,
                 const float* bih, const float* bhh, float* out,
                 int* flin_base, int* flout_base) {
    constexpr int H = (LAYER == 3) ? 64 : 128;
    constexpr int KT_H = H / 32;               // K-tiles for h@Whh
    constexpr int KT_X = (LAYER == 1) ? 1 : 4; // K-tiles for x@Wih
    constexpr int HP = H + 8;                  // padded LDS row (f16)
    constexpr int NWAVE = (LAYER == 3) ? 4 : 8;
    constexpr int LBUF = 2 * 16 * HP;          // f16 elems per tile (2 bufs)

    const int tid  = threadIdx.x;
    const int lane = tid & 63;
    const int wv   = tid >> 6;
    const int lr   = lane & 15;       // fragment row (batch) / col (j)
    const int lk   = lane >> 4;       // k-group 0..3
    const bool active = (wv < NWAVE);
    const int jcol = (wv & (NWAVE - 1)) * 16 + lr;
    const int bA = tA * 16, bB = tB * 16;

    _Float16 (*hldsA)[16][HP] = (_Float16 (*)[16][HP])smem;
    _Float16 (*hldsB)[16][HP] = (_Float16 (*)[16][HP])(smem + LBUF * 2);

    // ---- shared resident weights (f32 -> f16 once) ----
    h8 wbh[4][KT_H], wbx[4][KT_X];
    float bias[4];
    if (active) {
#pragma unroll
        for (int q = 0; q < 4; q++) {
#pragma unroll
            for (int kt = 0; kt < KT_H; kt++)
                wbh[q][kt] = cvt8(Whh + (size_t)(q * H + jcol) * H + kt * 32 + lk * 8);
            if constexpr (LAYER == 1) {
                wbx[q][0] = (lk == 0) ? cvt8(Wih + (size_t)(q * H + jcol) * 8) : h8{};
            } else {
#pragma unroll
                for (int kt = 0; kt < KT_X; kt++)
                    wbx[q][kt] = cvt8(Wih + (size_t)(q * H + jcol) * 128 + kt * 32 + lk * 8);
            }
            bias[q] = bih[q * H + jcol] + bhh[q * H + jcol];
        }
    }

    float cA[4] = {0.f, 0.f, 0.f, 0.f}, cB[4] = {0.f, 0.f, 0.f, 0.f};

    for (int i = tid; i < 2 * LBUF; i += 512) ((_Float16*)smem)[i] = (_Float16)0;
    __syncthreads();

    auto load_x = [&](int b0, int t, h8* xa) {
        if constexpr (LAYER == 1) {
            xa[0] = (lk == 0) ? cvt8(x + ((size_t)(b0 + lr) * T_ + t) * 8) : h8{};
        } else {
#pragma unroll
            for (int kt = 0; kt < KT_X; kt++)
                xa[kt] = *reinterpret_cast<const h8*>(
                    Oin + ((size_t)(b0 + lr) * T_ + t) * 128 + kt * 32 + lk * 8);
        }
    };

    // acc = bias + x @ Wih^T  (bias folded into accumulator init)
    auto xmfma = [&](const h8* xv, f4* ax) {
#pragma unroll
        for (int q = 0; q < 4; q++) ax[q] = f4{bias[q], bias[q], bias[q], bias[q]};
#pragma unroll
        for (int kt = 0; kt < KT_X; kt++)
#pragma unroll
            for (int q = 0; q < 4; q++)
                ax[q] = __builtin_amdgcn_mfma_f32_16x16x32_f16(xv[kt], wbx[q][kt], ax[q], 0, 0, 0);
    };

    h8 xsA[KT_X], xsB[KT_X];   // single x slot per tile: load early-interval,
    f4 accA[4], accB[4];       // consume late-interval (xproj for t+1)

    // one dual-tile interval; CUR is compile-time (0/1)
#define STEP2(T_EXPR, TT, CUR)                                                            \
    {                                                                                     \
        const int t = (T_EXPR);                                                           \
        /* prefetch next x for both tiles (consumed at end of this interval) */           \
        if ((TT) + 1 < TC_) { load_x(bA, t + 1, xsA); load_x(bB, t + 1, xsB); }           \
        h8 haA[KT_H], haB[KT_H];                                                          \
        _Pragma("unroll")                                                                 \
        for (int kt = 0; kt < KT_H; kt++) {                                               \
            haA[kt] = *reinterpret_cast<const h8*>(&hldsA[CUR][lr][kt * 32 + lk * 8]);    \
            haB[kt] = *reinterpret_cast<const h8*>(&hldsB[CUR][lr][kt * 32 + lk * 8]);    \
        }                                                                                 \
        _Pragma("unroll")                                                                 \
        for (int kt = 0; kt < KT_H; kt++)                                                 \
            _Pragma("unroll")                                                             \
            for (int q = 0; q < 4; q++) {                                                 \
                accA[q] = __builtin_amdgcn_mfma_f32_16x16x32_f16(haA[kt], wbh[q][kt],     \
                                                                 accA[q], 0, 0, 0);       \
                accB[q] = __builtin_amdgcn_mfma_f32_16x16x32_f16(haB[kt], wbh[q][kt],     \
                                                                 accB[q], 0, 0, 0);       \
            }                                                                             \
        _Pragma("unroll")                                                                 \
        for (int i = 0; i < 4; i++) {                                                     \
            const int row = lk * 4 + i;                                                   \
            {                                                                             \
                const float gi = sigmoidf_(accA[0][i]);                                   \
                const float gf = sigmoidf_(accA[1][i]);                                   \
                const float gg = tanhf_(accA[2][i]);                                      \
                const float go = sigmoidf_(accA[3][i]);                                   \
                cA[i] = gf * cA[i] + gi * gg;                                             \
                const float h = go * tanhf_(cA[i]);                                       \
                hldsA[(CUR) ^ 1][row][jcol] = (_Float16)h;                                \
                if constexpr (LAYER < 3) {                                                \
                    Oout[((size_t)(bA + row) * T_ + t) * 128 + jcol] = (_Float16)h;       \
                } else {                                                                  \
                    if (t == T_ - 1) out[(size_t)(bA + row) * 64 + jcol] = h;             \
                }                                                                         \
            }                                                                             \
            {                                                                             \
                const float gi = sigmoidf_(accB[0][i]);                                   \
                const float gf = sigmoidf_(accB[1][i]);                                   \
                const float gg = tanhf_(accB[2][i]);                                      \
                const float go = sigmoidf_(accB[3][i]);                                   \
                cB[i] = gf * cB[i] + gi * gg;                                             \
                const float h = go * tanhf_(cB[i]);                                       \
                hldsB[(CUR) ^ 1][row][jcol] = (_Float16)h;                                \
                if constexpr (LAYER < 3) {                                                \
                    Oout[((size_t)(bB + row) * T_ + t) * 128 + jcol] = (_Float16)h;       \
                } else {                                                                  \
                    if (t == T_ - 1) out[(size_t)(bB + row) * 64 + jcol] = h;             \
                }                                                                         \
            }                                                                             \
        }                                                                                 \
        if ((TT) + 1 < TC_) { xmfma(xsA, accA); xmfma(xsB, accB); }                       \
    }

    for (int ch = 0; ch < NC_; ch++) {
        // ---- consumer: wait for both input tiles' chunk ch ----
        if constexpr (LAYER > 1) {
            if (tid == 0) {
                while (__hip_atomic_load(flin_base + tA, __ATOMIC_RELAXED,
                                         __HIP_MEMORY_SCOPE_AGENT) < ch + 1)
                    __builtin_amdgcn_s_sleep(2);
                while (__hip_atomic_load(flin_base + tB, __ATOMIC_RELAXED,
                                         __HIP_MEMORY_SCOPE_AGENT) < ch + 1)
                    __builtin_amdgcn_s_sleep(2);
                __threadfence();   // agent acquire
            }
            __syncthreads();
        }
        const int t0 = ch * TC_;
        if (active) {
            load_x(bA, t0, xsA);
            load_x(bB, t0, xsB);
            xmfma(xsA, accA);      // chunk-head projections (unshadowed, 1/16)
            xmfma(xsB, accB);
        }

        for (int tb = 0; tb < TC_ / 2; tb++) {
            if (active) STEP2(t0 + 2 * tb, 2 * tb, 0);
            lds_barrier();
            if (active) STEP2(t0 + 2 * tb + 1, 2 * tb + 1, 1);
            lds_barrier();
        }

        // ---- producer: publish chunk ch for both tiles ----
        if constexpr (LAYER < 3) {
            asm volatile("s_waitcnt vmcnt(0)" ::: "memory");
            __syncthreads();
            if (tid == 0) {
                __threadfence();   // agent release
                __hip_atomic_store(flout_base + tA, ch + 1, __ATOMIC_RELAXED,
                                   __HIP_MEMORY_SCOPE_AGENT);
                __hip_atomic_store(flout_base + tB, ch + 1, __ATOMIC_RELAXED,
                                   __HIP_MEMORY_SCOPE_AGENT);
            }
        }
    }
#undef STEP2
}

__global__ __launch_bounds__(512, 2)
void mega_k(const float* __restrict__ x,
            const float* __restrict__ Wih1, const float* __restrict__ Whh1,
            const float* __restrict__ bih1, const float* __restrict__ bhh1,
            const float* __restrict__ Wih2, const float* __restrict__ Whh2,
            const float* __restrict__ bih2, const float* __restrict__ bhh2,
            const float* __restrict__ Wih3, const float* __restrict__ Whh3,
            const float* __restrict__ bih3, const float* __restrict__ bhh3,
            _Float16* __restrict__ O1, _Float16* __restrict__ O2,
            float* __restrict__ out, int* __restrict__ flags) {
    extern __shared__ char smem[];
    const int bid = blockIdx.x;
    if (bid < 16) {
        stage2<1>(2 * bid, 2 * bid + 1, smem, x, nullptr, O1,
                  Wih1, Whh1, bih1, bhh1, nullptr, nullptr, flags);
    } else if (bid < 32) {
        const int p = bid - 16;
        stage2<2>(2 * p, 2 * p + 1, smem, nullptr, O1, O2,
                  Wih2, Whh2, bih2, bhh2, nullptr, flags, flags + 32);
    } else {
        const int p = bid - 32;
        stage2<3>(2 * p, 2 * p + 1, smem, nullptr, O2, nullptr,
                  Wih3, Whh3, bih3, bhh3, out, flags + 32, nullptr);
    }
}

__global__ void zero_flags_k(int* flags) {
    if (threadIdx.x < 64)
        __hip_atomic_store(flags + threadIdx.x, 0, __ATOMIC_RELAXED,
                           __HIP_MEMORY_SCOPE_AGENT);
}

extern "C" void kernel_launch(void* const* d_in, const int* in_sizes, int n_in,
                              void* d_out, int out_size, void* d_ws, size_t ws_size,
                              hipStream_t stream) {
    const float* x = (const float*)d_in[0];
    float* out = (float*)d_out;

    char* ws = (char*)d_ws;
    _Float16* O1 = (_Float16*)ws;                         // 67,108,864 B
    _Float16* O2 = (_Float16*)(ws + (size_t)67108864);    // 67,108,864 B
    int* flags   = (int*)(ws + (size_t)134217728);        // 256 B
    (void)ws_size; (void)in_sizes; (void)n_in; (void)out_size;

    // LDS: 2 tiles * 2 bufs * 16 rows * 136 cols * 2B = 17408 B
    zero_flags_k<<<1, 64, 0, stream>>>(flags);
    mega_k<<<48, 512, 17408, stream>>>(
        x,
        (const float*)d_in[1], (const float*)d_in[2], (const float*)d_in[3], (const float*)d_in[4],
        (const float*)d_in[5], (const float*)d_in[6], (const float*)d_in[7], (const float*)d_in[8],
        (const float*)d_in[9], (const float*)d_in[10], (const float*)d_in[11], (const float*)d_in[12],
        O1, O2, out, flags);
}

// Round 12
// 1141.722 us; speedup vs baseline: 1.5282x; 1.5282x over previous
//
#include <hip/hip_runtime.h>

// 3-layer LSTM encoder. B=512, T=512, F=8, HID=128, EMB=64.
// R12: producer/consumer wave split. 96 blocks (3 stages x 32 tiles) x 1024thr:
//   waves 0-7  = recurrence: acc = ds_read(xg) ; acc += h@Whh ; pointwise ; h
//   waves 8-15 = projection: xg(t+1) = bias + x(t+1)@Wih via MFMA -> LDS ring
// Roles share ONE register file (wreg/acc/opf) so per-lane regs ~112 -> 4
// waves/SIMD, no spill. xg = [2][G][20] f32 ring (stride 20 => 2-way banks).
// lgkmcnt-only in-loop barrier; chunk flags as R8/R10. ws: [O1 67MB][O2 67MB][flags]

#define DEVI __device__ __forceinline__

typedef _Float16 h8 __attribute__((ext_vector_type(8)));
typedef float f4 __attribute__((ext_vector_type(4)));

static constexpr int T_ = 512, TC_ = 16, NC_ = T_ / TC_, XGP = 20;

DEVI float sigmoidf_(float x) {
    return __builtin_amdgcn_rcpf(1.f + __builtin_amdgcn_exp2f(x * -1.44269504f));
}
DEVI float tanhf_(float x) {
    return 2.f * __builtin_amdgcn_rcpf(1.f + __builtin_amdgcn_exp2f(x * -2.88539008f)) - 1.f;
}
DEVI h8 cvt8(const float* p) {
    const float4 a = *reinterpret_cast<const float4*>(p);
    const float4 b = *reinterpret_cast<const float4*>(p + 4);
    return h8{(_Float16)a.x, (_Float16)a.y, (_Float16)a.z, (_Float16)a.w,
              (_Float16)b.x, (_Float16)b.y, (_Float16)b.z, (_Float16)b.w};
}
DEVI void lds_barrier() {
    asm volatile("s_waitcnt lgkmcnt(0)\n\ts_barrier" ::: "memory");
}

// LAYER=1: H=128, x from f32 input (K=8 zero-padded), producer only
// LAYER=2: H=128, x from O1, writes O2, consumer+producer
// LAYER=3: H=64,  x from O2, writes out (t=511), consumer only
template <int LAYER>
DEVI void stage(int tile, char* smem, const float* x, const _Float16* Oin,
                _Float16* Oout, const float* Wih, const float* Whh,
                const float* bih, const float* bhh, float* out,
                int* flag_in, int* flag_out) {
    constexpr int H = (LAYER == 3) ? 64 : 128;
    constexpr int G = 4 * H;
    constexpr int KT_H = H / 32;               // rec K-tiles (4 or 2)
    constexpr int KT_X = (LAYER == 1) ? 1 : 4; // proj K-tiles
    constexpr int HP = H + 8;                  // padded h row (f16)
    constexpr int NWR = H / 16;                // rec waves active (8 or 4)
    constexpr int PNT = G / 128;               // proj N-tiles/wave (4 or 2)

    const int tid = threadIdx.x, lane = tid & 63, wv = tid >> 6;
    const int lr = lane & 15, lk = lane >> 4;
    const int b0 = tile * 16;
    const bool isrec = (wv < 8);
    const bool recact = (wv < NWR);

    float* xg = (float*)smem;                                  // [2][G][XGP] f32
    _Float16 (*h_lds)[16][HP] =
        (_Float16 (*)[16][HP])(smem + (size_t)2 * G * XGP * 4);

    // ---- unified per-lane register file, role-indexed ----
    h8 wreg[16];        // rec: wreg[kt*4+q]=Whh frag ; proj: wreg[nt*KT_X+kt]=Wih frag
    f4 acc[4];          // rec: gate acc ; proj: xg acc
    h8 opf[4];          // rec: h A-frags ; proj: x A-frags
    float pbias[4];     // proj only (bias folded into xg)
    float c[4] = {0.f, 0.f, 0.f, 0.f};   // rec cell state
    int jcol = 0, gc0 = 0;

    if (isrec) {
        jcol = (wv & (NWR - 1)) * 16 + lr;
        if (recact) {
#pragma unroll
            for (int kt = 0; kt < KT_H; kt++)
#pragma unroll
                for (int q = 0; q < 4; q++)
                    wreg[kt * 4 + q] = cvt8(Whh + (size_t)(q * H + jcol) * H + kt * 32 + lk * 8);
        }
    } else {
        const int pw = wv - 8;
        gc0 = pw * (16 * PNT);
#pragma unroll
        for (int nt = 0; nt < PNT; nt++) {
            const int gcol = gc0 + nt * 16 + lr;
            pbias[nt] = bih[gcol] + bhh[gcol];
            if constexpr (LAYER == 1) {
                wreg[nt] = (lk == 0) ? cvt8(Wih + (size_t)gcol * 8) : h8{};
            } else {
#pragma unroll
                for (int kt = 0; kt < KT_X; kt++)
                    wreg[nt * KT_X + kt] = cvt8(Wih + (size_t)gcol * 128 + kt * 32 + lk * 8);
            }
        }
    }

    for (int i = tid; i < 2 * 16 * HP; i += 1024)
        ((_Float16*)(smem + (size_t)2 * G * XGP * 4))[i] = (_Float16)0;
    __syncthreads();

    // proj: xg[t&1] = bias + x_t @ Wih^T   (proj waves only)
    auto proj_step = [&](int t) {
        if constexpr (LAYER == 1) {
            opf[0] = (lk == 0) ? cvt8(x + ((size_t)(b0 + lr) * T_ + t) * 8) : h8{};
        } else {
#pragma unroll
            for (int kt = 0; kt < KT_X; kt++)
                opf[kt] = *reinterpret_cast<const h8*>(
                    Oin + ((size_t)(b0 + lr) * T_ + t) * 128 + kt * 32 + lk * 8);
        }
#pragma unroll
        for (int nt = 0; nt < PNT; nt++)
            acc[nt] = f4{pbias[nt], pbias[nt], pbias[nt], pbias[nt]};
#pragma unroll
        for (int kt = 0; kt < KT_X; kt++)
#pragma unroll
            for (int nt = 0; nt < PNT; nt++)
                acc[nt] = __builtin_amdgcn_mfma_f32_16x16x32_f16(opf[kt], wreg[nt * KT_X + kt],
                                                                 acc[nt], 0, 0, 0);
        float* dst = xg + (size_t)(t & 1) * G * XGP;
#pragma unroll
        for (int nt = 0; nt < PNT; nt++)
            *reinterpret_cast<f4*>(dst + (gc0 + nt * 16 + lr) * XGP + lk * 4) = acc[nt];
    };

    for (int ch = 0; ch < NC_; ch++) {
        const int t0 = ch * TC_;
        // ---- chunk head: consumer flag wait (acquire), then proj fills xg(t0) ----
        if constexpr (LAYER > 1) {
            if (tid == 0) {
                while (__hip_atomic_load(flag_in, __ATOMIC_RELAXED,
                                         __HIP_MEMORY_SCOPE_AGENT) < ch + 1)
                    __builtin_amdgcn_s_sleep(2);
                __threadfence();
            }
        }
        __syncthreads();
        if (!isrec) proj_step(t0);       // slot t0&1 == 0
        lds_barrier();

        for (int tt = 0; tt < TC_; tt++) {
            const int t = t0 + tt;
            const int cur = t & 1;
            if (isrec) {
                if (recact) {
                    // acc init = ds_read of precomputed x-projection (+bias)
                    const float* src = xg + (size_t)cur * G * XGP;
#pragma unroll
                    for (int q = 0; q < 4; q++)
                        acc[q] = *reinterpret_cast<const f4*>(src + (q * H + jcol) * XGP + lk * 4);
#pragma unroll
                    for (int kt = 0; kt < KT_H; kt++)
                        opf[kt] = *reinterpret_cast<const h8*>(&h_lds[cur][lr][kt * 32 + lk * 8]);
#pragma unroll
                    for (int kt = 0; kt < KT_H; kt++)
#pragma unroll
                        for (int q = 0; q < 4; q++)
                            acc[q] = __builtin_amdgcn_mfma_f32_16x16x32_f16(opf[kt], wreg[kt * 4 + q],
                                                                            acc[q], 0, 0, 0);
#pragma unroll
                    for (int i = 0; i < 4; i++) {
                        const float gi = sigmoidf_(acc[0][i]);
                        const float gf = sigmoidf_(acc[1][i]);
                        const float gg = tanhf_(acc[2][i]);
                        const float go = sigmoidf_(acc[3][i]);
                        c[i] = gf * c[i] + gi * gg;
                        const float h = go * tanhf_(c[i]);
                        const int row = lk * 4 + i;
                        h_lds[cur ^ 1][row][jcol] = (_Float16)h;
                        if constexpr (LAYER < 3) {
                            Oout[((size_t)(b0 + row) * T_ + t) * 128 + jcol] = (_Float16)h;
                        } else {
                            if (t == T_ - 1) out[(size_t)(b0 + row) * 64 + jcol] = h;
                        }
                    }
                }
            } else {
                if (tt + 1 < TC_) proj_step(t + 1);   // writes slot cur^1 (disjoint)
            }
            lds_barrier();
        }

        // ---- chunk tail: drain stores, publish ----
        if constexpr (LAYER < 3) {
            asm volatile("s_waitcnt vmcnt(0)" ::: "memory");
        }
        __syncthreads();
        if (tid == 0) {
            if constexpr (LAYER < 3) {
                __threadfence();
                __hip_atomic_store(flag_out, ch + 1, __ATOMIC_RELAXED,
                                   __HIP_MEMORY_SCOPE_AGENT);
            }
        }
    }
}

__global__ __launch_bounds__(1024, 4)
void mega_k(const float* __restrict__ x,
            const float* __restrict__ Wih1, const float* __restrict__ Whh1,
            const float* __restrict__ bih1, const float* __restrict__ bhh1,
            const float* __restrict__ Wih2, const float* __restrict__ Whh2,
            const float* __restrict__ bih2, const float* __restrict__ bhh2,
            const float* __restrict__ Wih3, const float* __restrict__ Whh3,
            const float* __restrict__ bih3, const float* __restrict__ bhh3,
            _Float16* __restrict__ O1, _Float16* __restrict__ O2,
            float* __restrict__ out, int* __restrict__ flags) {
    extern __shared__ char smem[];
    const int bid = blockIdx.x;
    if (bid < 32) {
        stage<1>(bid, smem, x, nullptr, O1, Wih1, Whh1, bih1, bhh1, nullptr,
                 nullptr, flags + bid);
    } else if (bid < 64) {
        stage<2>(bid - 32, smem, nullptr, O1, O2, Wih2, Whh2, bih2, bhh2, nullptr,
                 flags + (bid - 32), flags + 32 + (bid - 32));
    } else {
        stage<3>(bid - 64, smem, nullptr, O2, nullptr, Wih3, Whh3, bih3, bhh3, out,
                 flags + 32 + (bid - 64), nullptr);
    }
}

__global__ void zero_flags_k(int* flags) {
    if (threadIdx.x < 64)
        __hip_atomic_store(flags + threadIdx.x, 0, __ATOMIC_RELAXED,
                           __HIP_MEMORY_SCOPE_AGENT);
}

extern "C" void kernel_launch(void* const* d_in, const int* in_sizes, int n_in,
                              void* d_out, int out_size, void* d_ws, size_t ws_size,
                              hipStream_t stream) {
    const float* x = (const float*)d_in[0];
    float* out = (float*)d_out;

    char* ws = (char*)d_ws;
    _Float16* O1 = (_Float16*)ws;                         // 67,108,864 B
    _Float16* O2 = (_Float16*)(ws + (size_t)67108864);    // 67,108,864 B
    int* flags   = (int*)(ws + (size_t)134217728);        // 256 B
    (void)ws_size; (void)in_sizes; (void)n_in; (void)out_size;

    // LDS: xg 2*512*20*4 = 81920 B + h 2*16*136*2 = 8704 B -> 90624 B
    zero_flags_k<<<1, 64, 0, stream>>>(flags);
    mega_k<<<96, 1024, 90624, stream>>>(
        x,
        (const float*)d_in[1], (const float*)d_in[2], (const float*)d_in[3], (const float*)d_in[4],
        (const float*)d_in[5], (const float*)d_in[6], (const float*)d_in[7], (const float*)d_in[8],
        (const float*)d_in[9], (const float*)d_in[10], (const float*)d_in[11], (const float*)d_in[12],
        O1, O2, out, flags);
}

// Round 13
// 765.454 us; speedup vs baseline: 2.2794x; 1.4916x over previous
//
#include <hip/hip_runtime.h>

// 3-layer LSTM encoder. B=512, T=512, F=8, HID=128, EMB=64.
// Pipelined mega-kernel: 96 blocks = 3 stages x 32 batch-tiles (R10 structure).
// R13: SINGLE CHANGE vs R10 — the step loop is NOT unrolled (#pragma unroll 1,
// body = one even/odd step pair). R10's compiler-unrolled 16-step chunk body
// (~20KB) was suspected I-cache-thrash; hot loop now ~2.5KB.
// Keeps: 2-step-ahead x prefetch (static xa/xb), acc ping-pong, x-MFMA in
// trans shadow, bias-folded acc init, lgkmcnt-only in-loop barrier.
// ws: [O1 67MB][O2 67MB][flags]

#define DEVI __device__ __forceinline__

typedef _Float16 h8 __attribute__((ext_vector_type(8)));
typedef float f4 __attribute__((ext_vector_type(4)));

static constexpr int T_ = 512, TC_ = 16, NC_ = T_ / TC_;

DEVI float sigmoidf_(float x) {
    return __builtin_amdgcn_rcpf(1.f + __builtin_amdgcn_exp2f(x * -1.44269504f));
}
DEVI float tanhf_(float x) {
    return 2.f * __builtin_amdgcn_rcpf(1.f + __builtin_amdgcn_exp2f(x * -2.88539008f)) - 1.f;
}

DEVI h8 cvt8(const float* p) {
    const float4 a = *reinterpret_cast<const float4*>(p);
    const float4 b = *reinterpret_cast<const float4*>(p + 4);
    return h8{(_Float16)a.x, (_Float16)a.y, (_Float16)a.z, (_Float16)a.w,
              (_Float16)b.x, (_Float16)b.y, (_Float16)b.z, (_Float16)b.w};
}

// LDS-only barrier: orders h_lds writes/reads without draining vmcnt.
DEVI void lds_barrier() {
    asm volatile("s_waitcnt lgkmcnt(0)\n\ts_barrier" ::: "memory");
}

// LAYER=1: H=128, x from f32 input (K=8 zero-padded), producer only
// LAYER=2: H=128, x from O1, writes O2, consumer+producer
// LAYER=3: H=64,  x from O2, writes out (t=511), consumer only
template <int LAYER>
DEVI void stage(int tile, char* smem, const float* x, const _Float16* Oin,
                _Float16* Oout, const float* Wih, const float* Whh,
                const float* bih, const float* bhh, float* out,
                int* flag_in, int* flag_out) {
    constexpr int H = (LAYER == 3) ? 64 : 128;
    constexpr int KT_H = H / 32;               // K-tiles for h@Whh
    constexpr int KT_X = (LAYER == 1) ? 1 : 4; // K-tiles for x@Wih
    constexpr int HP = H + 8;                  // padded LDS row (f16)
    constexpr int NWAVE = (LAYER == 3) ? 4 : 8;

    const int tid  = threadIdx.x;
    const int lane = tid & 63;
    const int wv   = tid >> 6;
    const int lr   = lane & 15;       // fragment row (batch) / col (j)
    const int lk   = lane >> 4;       // k-group 0..3
    const int b0   = tile * 16;
    const bool active = (wv < NWAVE);
    const int jcol = (wv & (NWAVE - 1)) * 16 + lr;

    _Float16 (*h_lds)[16][HP] = (_Float16 (*)[16][HP])smem;

    // ---- resident weight B-frags (f32 -> f16 once) ----
    h8 wbh[4][KT_H], wbx[4][KT_X];
    float bias[4];
    if (active) {
#pragma unroll
        for (int q = 0; q < 4; q++) {
#pragma unroll
            for (int kt = 0; kt < KT_H; kt++)
                wbh[q][kt] = cvt8(Whh + (size_t)(q * H + jcol) * H + kt * 32 + lk * 8);
            if constexpr (LAYER == 1) {
                wbx[q][0] = (lk == 0) ? cvt8(Wih + (size_t)(q * H + jcol) * 8) : h8{};
            } else {
#pragma unroll
                for (int kt = 0; kt < KT_X; kt++)
                    wbx[q][kt] = cvt8(Wih + (size_t)(q * H + jcol) * 128 + kt * 32 + lk * 8);
            }
            bias[q] = bih[q * H + jcol] + bhh[q * H + jcol];
        }
    }

    float c[4] = {0.f, 0.f, 0.f, 0.f};

    for (int i = tid; i < 2 * 16 * HP; i += 512) ((_Float16*)smem)[i] = (_Float16)0;
    __syncthreads();

    auto load_x = [&](int t, h8* xa) {
        if constexpr (LAYER == 1) {
            xa[0] = (lk == 0) ? cvt8(x + ((size_t)(b0 + lr) * T_ + t) * 8) : h8{};
        } else {
#pragma unroll
            for (int kt = 0; kt < KT_X; kt++)
                xa[kt] = *reinterpret_cast<const h8*>(
                    Oin + ((size_t)(b0 + lr) * T_ + t) * 128 + kt * 32 + lk * 8);
        }
    };

    // ax = bias + x @ Wih^T  (bias folded into accumulator init)
    auto xmfma = [&](const h8* xv, f4* ax) {
#pragma unroll
        for (int q = 0; q < 4; q++) ax[q] = f4{bias[q], bias[q], bias[q], bias[q]};
#pragma unroll
        for (int kt = 0; kt < KT_X; kt++)
#pragma unroll
            for (int q = 0; q < 4; q++)
                ax[q] = __builtin_amdgcn_mfma_f32_16x16x32_f16(xv[kt], wbx[q][kt], ax[q], 0, 0, 0);
    };

    h8 xa[KT_X], xb[KT_X];    // static 2-slot prefetch: xa=even-step x, xb=odd
    f4 accA[4], accB[4];      // static acc ping-pong

    // one step; slot choices are compile-time via macro args (CUR 0/1)
#define STEP_BODY(T_EXPR, TT, CUR, ACCU, ACCN, XLOAD, XPROJ)                              \
    {                                                                                     \
        const int t = (T_EXPR);                                                           \
        h8 ha[KT_H];                                                                      \
        _Pragma("unroll")                                                                 \
        for (int kt = 0; kt < KT_H; kt++)                                                 \
            ha[kt] = *reinterpret_cast<const h8*>(&h_lds[CUR][lr][kt * 32 + lk * 8]);     \
        _Pragma("unroll")                                                                 \
        for (int kt = 0; kt < KT_H; kt++)                                                 \
            _Pragma("unroll")                                                             \
            for (int q = 0; q < 4; q++)                                                   \
                ACCU[q] = __builtin_amdgcn_mfma_f32_16x16x32_f16(ha[kt], wbh[q][kt],      \
                                                                 ACCU[q], 0, 0, 0);       \
        if ((TT) + 2 < TC_) load_x(t + 2, XLOAD);  /* consumed end of NEXT step */        \
        _Pragma("unroll")                                                                 \
        for (int i = 0; i < 4; i++) {                                                     \
            const float gi = sigmoidf_(ACCU[0][i]);                                       \
            const float gf = sigmoidf_(ACCU[1][i]);                                       \
            const float gg = tanhf_(ACCU[2][i]);                                          \
            const float go = sigmoidf_(ACCU[3][i]);                                       \
            c[i] = gf * c[i] + gi * gg;                                                   \
            const float h = go * tanhf_(c[i]);                                            \
            const int row = lk * 4 + i;                                                   \
            h_lds[(CUR) ^ 1][row][jcol] = (_Float16)h;                                    \
            if constexpr (LAYER < 3) {                                                    \
                Oout[((size_t)(b0 + row) * T_ + t) * 128 + jcol] = (_Float16)h;           \
            } else {                                                                      \
                if (t == T_ - 1) out[(size_t)(b0 + row) * 64 + jcol] = h;                 \
            }                                                                             \
        }                                                                                 \
        if ((TT) + 1 < TC_) xmfma(XPROJ, ACCN);  /* next step's x-proj in trans shadow */ \
    }

#pragma unroll 1
    for (int ch = 0; ch < NC_; ch++) {
        // ---- consumer: wait for input chunk ch ----
        if constexpr (LAYER > 1) {
            if (tid == 0) {
                while (__hip_atomic_load(flag_in, __ATOMIC_RELAXED,
                                         __HIP_MEMORY_SCOPE_AGENT) < ch + 1)
                    __builtin_amdgcn_s_sleep(2);
                __threadfence();   // agent acquire: inv caches before data reads
            }
            __syncthreads();
        }
        const int t0 = ch * TC_;
        if (active) {
            load_x(t0, xa);
            load_x(t0 + 1, xb);
            xmfma(xa, accA);       // chunk-head projection (unshadowed, 1/16 steps)
        }

#pragma unroll 1
        for (int tb = 0; tb < TC_ / 2; tb++) {
            // even step: reads h_lds[0] -> writes h_lds[1]
            if (active) STEP_BODY(t0 + 2 * tb, 2 * tb, 0, accA, accB, xa, xb);
            lds_barrier();
            // odd step: reads h_lds[1] -> writes h_lds[0]
            if (active) STEP_BODY(t0 + 2 * tb + 1, 2 * tb + 1, 1, accB, accA, xb, xa);
            lds_barrier();
        }

        // ---- producer: publish chunk ch (drain own stores first) ----
        if constexpr (LAYER < 3) {
            asm volatile("s_waitcnt vmcnt(0)" ::: "memory");
            __syncthreads();
            if (tid == 0) {
                __threadfence();   // agent release: visible at coherent point
                __hip_atomic_store(flag_out, ch + 1, __ATOMIC_RELAXED,
                                   __HIP_MEMORY_SCOPE_AGENT);
            }
        }
    }
#undef STEP_BODY
}

__global__ __launch_bounds__(512, 1)
void mega_k(const float* __restrict__ x,
            const float* __restrict__ Wih1, const float* __restrict__ Whh1,
            const float* __restrict__ bih1, const float* __restrict__ bhh1,
            const float* __restrict__ Wih2, const float* __restrict__ Whh2,
            const float* __restrict__ bih2, const float* __restrict__ bhh2,
            const float* __restrict__ Wih3, const float* __restrict__ Whh3,
            const float* __restrict__ bih3, const float* __restrict__ bhh3,
            _Float16* __restrict__ O1, _Float16* __restrict__ O2,
            float* __restrict__ out, int* __restrict__ flags) {
    extern __shared__ char smem[];
    const int bid = blockIdx.x;
    if (bid < 32) {
        stage<1>(bid, smem, x, nullptr, O1, Wih1, Whh1, bih1, bhh1, nullptr,
                 nullptr, flags + bid);
    } else if (bid < 64) {
        stage<2>(bid - 32, smem, nullptr, O1, O2, Wih2, Whh2, bih2, bhh2, nullptr,
                 flags + (bid - 32), flags + 32 + (bid - 32));
    } else {
        stage<3>(bid - 64, smem, nullptr, O2, nullptr, Wih3, Whh3, bih3, bhh3, out,
                 flags + 32 + (bid - 64), nullptr);
    }
}

__global__ void zero_flags_k(int* flags) {
    if (threadIdx.x < 64)
        __hip_atomic_store(flags + threadIdx.x, 0, __ATOMIC_RELAXED,
                           __HIP_MEMORY_SCOPE_AGENT);
}

extern "C" void kernel_launch(void* const* d_in, const int* in_sizes, int n_in,
                              void* d_out, int out_size, void* d_ws, size_t ws_size,
                              hipStream_t stream) {
    const float* x = (const float*)d_in[0];
    float* out = (float*)d_out;

    char* ws = (char*)d_ws;
    _Float16* O1 = (_Float16*)ws;                         // 67,108,864 B
    _Float16* O2 = (_Float16*)(ws + (size_t)67108864);    // 67,108,864 B
    int* flags   = (int*)(ws + (size_t)134217728);        // 256 B
    (void)ws_size; (void)in_sizes; (void)n_in; (void)out_size;

    zero_flags_k<<<1, 64, 0, stream>>>(flags);
    mega_k<<<96, 512, 8704, stream>>>(
        x,
        (const float*)d_in[1], (const float*)d_in[2], (const float*)d_in[3], (const float*)d_in[4],
        (const float*)d_in[5], (const float*)d_in[6], (const float*)d_in[7], (const float*)d_in[8],
        (const float*)d_in[9], (const float*)d_in[10], (const float*)d_in[11], (const float*)d_in[12],
        O1, O2, out, flags);
}

// Round 14
// 729.902 us; speedup vs baseline: 2.3904x; 1.0487x over previous
//
#include <hip/hip_runtime.h>

// 3-layer LSTM encoder. B=512, T=512, F=8, HID=128, EMB=64.
// Pipelined mega-kernel: 96 blocks = 3 stages x 32 batch-tiles (R10 structure).
// R14: (1) x-MFMA at step HEAD (issues under h ds_read latency; no acc
// ping-pong, no pre-barrier MFMA tail); (2) x parity-slot reuse (consume at
// head, reload t+2 later; 2-step slack); (3) pointwise trans batched
// (16 exp2 then rcps). lgkmcnt-only in-loop barrier; chunk flags as R8.
// ws: [O1 67MB][O2 67MB][flags]

#define DEVI __device__ __forceinline__

typedef _Float16 h8 __attribute__((ext_vector_type(8)));
typedef float f4 __attribute__((ext_vector_type(4)));

static constexpr int T_ = 512, TC_ = 16, NC_ = T_ / TC_;

DEVI float rcpf_(float x) { return __builtin_amdgcn_rcpf(x); }
DEVI float exp2f_(float x) { return __builtin_amdgcn_exp2f(x); }

DEVI h8 cvt8(const float* p) {
    const float4 a = *reinterpret_cast<const float4*>(p);
    const float4 b = *reinterpret_cast<const float4*>(p + 4);
    return h8{(_Float16)a.x, (_Float16)a.y, (_Float16)a.z, (_Float16)a.w,
              (_Float16)b.x, (_Float16)b.y, (_Float16)b.z, (_Float16)b.w};
}

// LDS-only barrier: orders h_lds writes/reads without draining vmcnt.
DEVI void lds_barrier() {
    asm volatile("s_waitcnt lgkmcnt(0)\n\ts_barrier" ::: "memory");
}

// LAYER=1: H=128, x from f32 input (K=8 zero-padded), producer only
// LAYER=2: H=128, x from O1, writes O2, consumer+producer
// LAYER=3: H=64,  x from O2, writes out (t=511), consumer only
template <int LAYER>
DEVI void stage(int tile, char* smem, const float* x, const _Float16* Oin,
                _Float16* Oout, const float* Wih, const float* Whh,
                const float* bih, const float* bhh, float* out,
                int* flag_in, int* flag_out) {
    constexpr int H = (LAYER == 3) ? 64 : 128;
    constexpr int KT_H = H / 32;               // K-tiles for h@Whh
    constexpr int KT_X = (LAYER == 1) ? 1 : 4; // K-tiles for x@Wih
    constexpr int HP = H + 8;                  // padded LDS row (f16)
    constexpr int NWAVE = (LAYER == 3) ? 4 : 8;

    const int tid  = threadIdx.x;
    const int lane = tid & 63;
    const int wv   = tid >> 6;
    const int lr   = lane & 15;       // fragment row (batch) / col (j)
    const int lk   = lane >> 4;       // k-group 0..3
    const int b0   = tile * 16;
    const bool active = (wv < NWAVE);
    const int jcol = (wv & (NWAVE - 1)) * 16 + lr;

    _Float16 (*h_lds)[16][HP] = (_Float16 (*)[16][HP])smem;

    // ---- resident weight B-frags (f32 -> f16 once) ----
    h8 wbh[4][KT_H], wbx[4][KT_X];
    float bias[4];
    if (active) {
#pragma unroll
        for (int q = 0; q < 4; q++) {
#pragma unroll
            for (int kt = 0; kt < KT_H; kt++)
                wbh[q][kt] = cvt8(Whh + (size_t)(q * H + jcol) * H + kt * 32 + lk * 8);
            if constexpr (LAYER == 1) {
                wbx[q][0] = (lk == 0) ? cvt8(Wih + (size_t)(q * H + jcol) * 8) : h8{};
            } else {
#pragma unroll
                for (int kt = 0; kt < KT_X; kt++)
                    wbx[q][kt] = cvt8(Wih + (size_t)(q * H + jcol) * 128 + kt * 32 + lk * 8);
            }
            bias[q] = bih[q * H + jcol] + bhh[q * H + jcol];
        }
    }

    float c[4] = {0.f, 0.f, 0.f, 0.f};

    for (int i = tid; i < 2 * 16 * HP; i += 512) ((_Float16*)smem)[i] = (_Float16)0;
    __syncthreads();

    auto load_x = [&](int t, h8* xa) {
        if constexpr (LAYER == 1) {
            xa[0] = (lk == 0) ? cvt8(x + ((size_t)(b0 + lr) * T_ + t) * 8) : h8{};
        } else {
#pragma unroll
            for (int kt = 0; kt < KT_X; kt++)
                xa[kt] = *reinterpret_cast<const h8*>(
                    Oin + ((size_t)(b0 + lr) * T_ + t) * 128 + kt * 32 + lk * 8);
        }
    };

    h8 xa[KT_X], xb[KT_X];    // parity slots: xa = even-step x, xb = odd-step x

    // one step; CUR compile-time; XS = this step's x slot (consumed at head,
    // reloaded with x(t+2) after the MFMA block -> 2-step slack preserved)
#define STEP_BODY(T_EXPR, TT, CUR, XS)                                                    \
    {                                                                                     \
        const int t = (T_EXPR);                                                           \
        /* h ds_read issued first; x-MFMA below issues under its latency */               \
        h8 ha[KT_H];                                                                      \
        _Pragma("unroll")                                                                 \
        for (int kt = 0; kt < KT_H; kt++)                                                 \
            ha[kt] = *reinterpret_cast<const h8*>(&h_lds[CUR][lr][kt * 32 + lk * 8]);     \
        f4 acc[4];                                                                        \
        _Pragma("unroll")                                                                 \
        for (int q = 0; q < 4; q++) acc[q] = f4{bias[q], bias[q], bias[q], bias[q]};      \
        _Pragma("unroll")                                                                 \
        for (int kt = 0; kt < KT_X; kt++)                                                 \
            _Pragma("unroll")                                                             \
            for (int q = 0; q < 4; q++)                                                   \
                acc[q] = __builtin_amdgcn_mfma_f32_16x16x32_f16(XS[kt], wbx[q][kt],       \
                                                                acc[q], 0, 0, 0);         \
        _Pragma("unroll")                                                                 \
        for (int kt = 0; kt < KT_H; kt++)                                                 \
            _Pragma("unroll")                                                             \
            for (int q = 0; q < 4; q++)                                                   \
                acc[q] = __builtin_amdgcn_mfma_f32_16x16x32_f16(ha[kt], wbh[q][kt],       \
                                                                acc[q], 0, 0, 0);         \
        if ((TT) + 2 < TC_) load_x(t + 2, XS);  /* refill same parity slot */             \
        /* pointwise: batch the 16 exp2 first, then rcp/combine per cell */               \
        float e0[4], e1[4], e2[4], e3[4];                                                 \
        _Pragma("unroll")                                                                 \
        for (int i = 0; i < 4; i++) {                                                     \
            e0[i] = exp2f_(acc[0][i] * -1.44269504f);                                     \
            e1[i] = exp2f_(acc[1][i] * -1.44269504f);                                     \
            e2[i] = exp2f_(acc[2][i] * -2.88539008f);                                     \
            e3[i] = exp2f_(acc[3][i] * -1.44269504f);                                     \
        }                                                                                 \
        _Pragma("unroll")                                                                 \
        for (int i = 0; i < 4; i++) {                                                     \
            const float gi = rcpf_(1.f + e0[i]);                                          \
            const float gf = rcpf_(1.f + e1[i]);                                          \
            const float gg = 2.f * rcpf_(1.f + e2[i]) - 1.f;                              \
            const float go = rcpf_(1.f + e3[i]);                                          \
            c[i] = gf * c[i] + gi * gg;                                                   \
            const float th = 2.f * rcpf_(1.f + exp2f_(c[i] * -2.88539008f)) - 1.f;        \
            const float h = go * th;                                                      \
            const int row = lk * 4 + i;                                                   \
            h_lds[(CUR) ^ 1][row][jcol] = (_Float16)h;                                    \
            if constexpr (LAYER < 3) {                                                    \
                Oout[((size_t)(b0 + row) * T_ + t) * 128 + jcol] = (_Float16)h;           \
            } else {                                                                      \
                if (t == T_ - 1) out[(size_t)(b0 + row) * 64 + jcol] = h;                 \
            }                                                                             \
        }                                                                                 \
    }

    for (int ch = 0; ch < NC_; ch++) {
        // ---- consumer: wait for input chunk ch ----
        if constexpr (LAYER > 1) {
            if (tid == 0) {
                while (__hip_atomic_load(flag_in, __ATOMIC_RELAXED,
                                         __HIP_MEMORY_SCOPE_AGENT) < ch + 1)
                    __builtin_amdgcn_s_sleep(2);
                __threadfence();   // agent acquire: inv caches before data reads
            }
            __syncthreads();
        }
        const int t0 = ch * TC_;
        if (active) {
            load_x(t0, xa);
            load_x(t0 + 1, xb);
        }

        for (int tb = 0; tb < TC_ / 2; tb++) {
            // even step: reads h_lds[0] -> writes h_lds[1]
            if (active) STEP_BODY(t0 + 2 * tb, 2 * tb, 0, xa);
            lds_barrier();
            // odd step: reads h_lds[1] -> writes h_lds[0]
            if (active) STEP_BODY(t0 + 2 * tb + 1, 2 * tb + 1, 1, xb);
            lds_barrier();
        }

        // ---- producer: publish chunk ch (drain own stores first) ----
        if constexpr (LAYER < 3) {
            asm volatile("s_waitcnt vmcnt(0)" ::: "memory");
            __syncthreads();
            if (tid == 0) {
                __threadfence();   // agent release: visible at coherent point
                __hip_atomic_store(flag_out, ch + 1, __ATOMIC_RELAXED,
                                   __HIP_MEMORY_SCOPE_AGENT);
            }
        }
    }
#undef STEP_BODY
}

__global__ __launch_bounds__(512, 1)
void mega_k(const float* __restrict__ x,
            const float* __restrict__ Wih1, const float* __restrict__ Whh1,
            const float* __restrict__ bih1, const float* __restrict__ bhh1,
            const float* __restrict__ Wih2, const float* __restrict__ Whh2,
            const float* __restrict__ bih2, const float* __restrict__ bhh2,
            const float* __restrict__ Wih3, const float* __restrict__ Whh3,
            const float* __restrict__ bih3, const float* __restrict__ bhh3,
            _Float16* __restrict__ O1, _Float16* __restrict__ O2,
            float* __restrict__ out, int* __restrict__ flags) {
    extern __shared__ char smem[];
    const int bid = blockIdx.x;
    if (bid < 32) {
        stage<1>(bid, smem, x, nullptr, O1, Wih1, Whh1, bih1, bhh1, nullptr,
                 nullptr, flags + bid);
    } else if (bid < 64) {
        stage<2>(bid - 32, smem, nullptr, O1, O2, Wih2, Whh2, bih2, bhh2, nullptr,
                 flags + (bid - 32), flags + 32 + (bid - 32));
    } else {
        stage<3>(bid - 64, smem, nullptr, O2, nullptr, Wih3, Whh3, bih3, bhh3, out,
                 flags + 32 + (bid - 64), nullptr);
    }
}

__global__ void zero_flags_k(int* flags) {
    if (threadIdx.x < 64)
        __hip_atomic_store(flags + threadIdx.x, 0, __ATOMIC_RELAXED,
                           __HIP_MEMORY_SCOPE_AGENT);
}

extern "C" void kernel_launch(void* const* d_in, const int* in_sizes, int n_in,
                              void* d_out, int out_size, void* d_ws, size_t ws_size,
                              hipStream_t stream) {
    const float* x = (const float*)d_in[0];
    float* out = (float*)d_out;

    char* ws = (char*)d_ws;
    _Float16* O1 = (_Float16*)ws;                         // 67,108,864 B
    _Float16* O2 = (_Float16*)(ws + (size_t)67108864);    // 67,108,864 B
    int* flags   = (int*)(ws + (size_t)134217728);        // 256 B
    (void)ws_size; (void)in_sizes; (void)n_in; (void)out_size;

    zero_flags_k<<<1, 64, 0, stream>>>(flags);
    mega_k<<<96, 512, 8704, stream>>>(
        x,
        (const float*)d_in[1], (const float*)d_in[2], (const float*)d_in[3], (const float*)d_in[4],
        (const float*)d_in[5], (const float*)d_in[6], (const float*)d_in[7], (const float*)d_in[8],
        (const float*)d_in[9], (const float*)d_in[10], (const float*)d_in[11], (const float*)d_in[12],
        O1, O2, out, flags);
}